// Round 4
// baseline (28.497 us; speedup 1.0000x reference)
//
#include <hip/hip_runtime.h>

// Live computation of the reference (everything else is dead code):
//   inpt[384] = concat(x[64], prev_output[64], state[256])
//   h1[1024]  = relu(w1_0 @ inpt + b1_0)   w1_0: (1024,384) row-major
//   h2[1024]  = relu(w1_1 @ h1   + b1_1)   w1_1: (1024,1024)
//   out[64]   = relu(w1_2 @ h2   + b1_2)   w1_2: (64,1024)
//
// ONE compute kernel, 256 blocks x 256 threads (co-resident: <=1 block/CU,
// capacity ~8/CU). Sync design tuned for gfx950 cache semantics:
//  - release fetch_add per block  -> buffer_wbl2 only (writeback, NO inv)
//  - poll with RELAXED loads      -> no buffer_inv per poll iteration
//  - exactly ONE acquire per block once condition met -> one L2 inv each
//  - layer-3 fan-in via private slots + last-arriver reduction: ZERO atomicAdd
// Counters must start at 0 each call: 256-byte memset node (d_ws poisoned
// once, never re-poisoned between replays).

#define NBLK 256

__device__ __forceinline__ float wave_reduce_sum(float v) {
    v += __shfl_xor(v, 32, 64);
    v += __shfl_xor(v, 16, 64);
    v += __shfl_xor(v, 8, 64);
    v += __shfl_xor(v, 4, 64);
    v += __shfl_xor(v, 2, 64);
    v += __shfl_xor(v, 1, 64);
    return v;
}

__global__ void __launch_bounds__(256, 2) smrnn_one(
        const float* __restrict__ x, const float* __restrict__ po,
        const float* __restrict__ st,
        const float* __restrict__ w0, const float* __restrict__ b0,
        const float* __restrict__ w1, const float* __restrict__ b1,
        const float* __restrict__ w2, const float* __restrict__ b2,
        float* __restrict__ h1, float* __restrict__ ws_part,
        unsigned int* __restrict__ ctr1, unsigned int* __restrict__ ctr2,
        float* __restrict__ out) {
    __shared__ float s_in[1024];
    __shared__ float s_h2[4];
    __shared__ float s_red[4][64];
    __shared__ unsigned int s_tok;

    const int t = threadIdx.x;
    const int lane = t & 63;
    const int wave = t >> 6;
    const int blk = blockIdx.x;

    // ---- stage inpt[384] = concat(x, prev_output, state) ----
    for (int i = t; i < 384; i += 256) {
        float v;
        if (i < 64)       v = x[i];
        else if (i < 128) v = po[i - 64];
        else              v = st[i - 128];
        s_in[i] = v;
    }
    __syncthreads();

    // ---- layer 1: h1[r] = relu(w0[r,:] . inpt + b0[r]), r = 4*blk+wave ----
    {
        const int r = blk * 4 + wave;
        const float* wr = w0 + (size_t)r * 384;
        float acc = 0.f;
        {
            const int idx = lane * 4;  // first 256 floats
            float4 wv = *reinterpret_cast<const float4*>(wr + idx);
            float4 iv = *reinterpret_cast<const float4*>(s_in + idx);
            acc += wv.x * iv.x + wv.y * iv.y + wv.z * iv.z + wv.w * iv.w;
        }
        {
            const int idx = 256 + lane * 2;  // last 128 floats
            float2 wv = *reinterpret_cast<const float2*>(wr + idx);
            float2 iv = *reinterpret_cast<const float2*>(s_in + idx);
            acc += wv.x * iv.x + wv.y * iv.y;
        }
        acc = wave_reduce_sum(acc);
        if (lane == 0) h1[r] = fmaxf(acc + b0[r], 0.f);
    }

    // ---- grid barrier (lean): release add, relaxed poll, single acquire ----
    __syncthreads();  // drains vmcnt(0): h1 stores are in (at least) local L2
    if (t == 0) {
        __hip_atomic_fetch_add(ctr1, 1u, __ATOMIC_RELEASE,
                               __HIP_MEMORY_SCOPE_AGENT);  // wbl2, no inv
        while (__hip_atomic_load(ctr1, __ATOMIC_RELAXED,
                                 __HIP_MEMORY_SCOPE_AGENT) < NBLK) {
            __builtin_amdgcn_s_sleep(8);
        }
        (void)__hip_atomic_load(ctr1, __ATOMIC_ACQUIRE,
                                __HIP_MEMORY_SCOPE_AGENT);  // one inv per block
    }
    __syncthreads();

    // ---- stage h1[1024] into LDS (float4-coalesced) ----
    {
        float4 v = *reinterpret_cast<const float4*>(h1 + t * 4);
        *reinterpret_cast<float4*>(s_in + t * 4) = v;
    }
    __syncthreads();

    // ---- layer 2: s_h2[wave] = relu(w1[r,:] . h1 + b1[r]), r = 4*blk+wave ----
    {
        const int r = blk * 4 + wave;
        const float* wr = w1 + (size_t)r * 1024;
        float acc = 0.f;
#pragma unroll
        for (int it = 0; it < 4; ++it) {
            const int idx = it * 256 + lane * 4;
            float4 wv = *reinterpret_cast<const float4*>(wr + idx);
            float4 iv = *reinterpret_cast<const float4*>(s_in + idx);
            acc += wv.x * iv.x + wv.y * iv.y + wv.z * iv.z + wv.w * iv.w;
        }
        acc = wave_reduce_sum(acc);
        if (lane == 0) s_h2[wave] = fmaxf(acc + b1[r], 0.f);
    }
    __syncthreads();

    // ---- layer 3 partials to private slot (plain stores, no atomics) ----
    if (wave == 0) {
        const float* w2r = w2 + (size_t)lane * 1024 + blk * 4;
        float4 wv = *reinterpret_cast<const float4*>(w2r);
        float p = wv.x * s_h2[0] + wv.y * s_h2[1] + wv.z * s_h2[2] + wv.w * s_h2[3];
        ws_part[blk * 64 + lane] = p;
    }
    __syncthreads();  // drains vmcnt(0): slot stores complete

    if (t == 0) {
        s_tok = __hip_atomic_fetch_add(ctr2, 1u, __ATOMIC_RELEASE,
                                       __HIP_MEMORY_SCOPE_AGENT);
    }
    __syncthreads();

    // ---- last arriver reduces 256x64 slab, applies bias+ReLU ----
    if (s_tok == NBLK - 1) {
        if (t == 0) {
            (void)__hip_atomic_load(ctr2, __ATOMIC_ACQUIRE,
                                    __HIP_MEMORY_SCOPE_AGENT);  // one inv
        }
        __syncthreads();
        // thread (wave,lane) sums blocks {4k+wave}, k=0..63, at column lane
        float acc = 0.f;
        const float* base = ws_part + wave * 64 + lane;
#pragma unroll 8
        for (int k = 0; k < 64; ++k) {
            acc += base[k * 4 * 64];
        }
        s_red[wave][lane] = acc;
        __syncthreads();
        if (wave == 0) {
            float tot = s_red[0][lane] + s_red[1][lane] + s_red[2][lane] +
                        s_red[3][lane];
            out[lane] = fmaxf(tot + b2[lane], 0.f);
        }
    }
}

extern "C" void kernel_launch(void* const* d_in, const int* in_sizes, int n_in,
                              void* d_out, int out_size, void* d_ws, size_t ws_size,
                              hipStream_t stream) {
    // setup_inputs() dict order:
    // 0:x 1:w1_0 2:b1_0 3:w1_1 4:b1_1 5:w1_2 6:b1_2
    // 7..16: w2_*/b2_*  17..26: w3_*/b3_*
    // 27: prev_output 28: state 29: prev_weight_change 30: prev_bias_change
    const float* x    = (const float*)d_in[0];
    const float* w1_0 = (const float*)d_in[1];
    const float* b1_0 = (const float*)d_in[2];
    const float* w1_1 = (const float*)d_in[3];
    const float* b1_1 = (const float*)d_in[4];
    const float* w1_2 = (const float*)d_in[5];
    const float* b1_2 = (const float*)d_in[6];
    const float* po   = (const float*)d_in[27];
    const float* st   = (const float*)d_in[28];

    float* out = (float*)d_out;                        // 64 floats
    float* ws_f = (float*)d_ws;
    unsigned int* ctr1 = (unsigned int*)d_ws;          // byte 0
    unsigned int* ctr2 = (unsigned int*)d_ws + 32;     // byte 128
    float* h1      = ws_f + 256;                       // 1 KiB offset, 1024 f
    float* ws_part = ws_f + 2048;                      // 8 KiB offset, 16384 f

    hipMemsetAsync(d_ws, 0, 256, stream);              // zero both counters
    smrnn_one<<<NBLK, 256, 0, stream>>>(x, po, st,
                                        w1_0, b1_0, w1_1, b1_1, w1_2, b1_2,
                                        h1, ws_part, ctr1, ctr2, out);
}

// Round 5
// 13.583 us; speedup vs baseline: 2.0979x; 2.0979x over previous
//
#include <hip/hip_runtime.h>

// Live computation of the reference (everything else is dead code):
//   inpt[384] = concat(x[64], prev_output[64], state[256])
//   h1[1024]  = relu(w1_0 @ inpt + b1_0)   w1_0: (1024,384) row-major
//   h2[1024]  = relu(w1_1 @ h1   + b1_1)   w1_1: (1024,1024)
//   out[64]   = relu(w1_2 @ h2   + b1_2)   w1_2: (64,1024)
//
// R1-R3 established: intra-kernel device-scope sync costs 5-25 us on gfx950
// (wbl2/inv storms, cross-XCD atomics) vs ~3 us per kernel boundary.
// So: 3 plain dispatches, minimal-latency bodies, max occupancy.
//   K2/K3: ONE ROW PER BLOCK (K=1024 -> 1 float4/thread + block reduce):
//   1024 blocks -> 4 blocks/CU -> 16 waves/CU (vs 4 in R0).

__device__ __forceinline__ float wave_reduce_sum(float v) {
    v += __shfl_xor(v, 32, 64);
    v += __shfl_xor(v, 16, 64);
    v += __shfl_xor(v, 8, 64);
    v += __shfl_xor(v, 4, 64);
    v += __shfl_xor(v, 2, 64);
    v += __shfl_xor(v, 1, 64);
    return v;
}

// Layer 1: K = 384, row per wave, 256 blocks x 256 threads.
__global__ void __launch_bounds__(256) fc_relu_concat(
        const float* __restrict__ x, const float* __restrict__ po,
        const float* __restrict__ st,
        const float* __restrict__ w, const float* __restrict__ b,
        float* __restrict__ out) {
    __shared__ float s_in[384];
    const int t = threadIdx.x;
    for (int i = t; i < 384; i += 256) {
        float v;
        if (i < 64)       v = x[i];
        else if (i < 128) v = po[i - 64];
        else              v = st[i - 128];
        s_in[i] = v;
    }
    __syncthreads();

    const int wave = t >> 6;
    const int lane = t & 63;
    const int r = blockIdx.x * 4 + wave;   // [0,1024)

    const float* wr = w + (size_t)r * 384;
    float acc = 0.f;
    {
        const int idx = lane * 4;          // first 256 floats
        float4 wv = *reinterpret_cast<const float4*>(wr + idx);
        float4 iv = *reinterpret_cast<const float4*>(s_in + idx);
        acc += wv.x * iv.x + wv.y * iv.y + wv.z * iv.z + wv.w * iv.w;
    }
    {
        const int idx = 256 + lane * 2;    // last 128 floats
        float2 wv = *reinterpret_cast<const float2*>(wr + idx);
        float2 iv = *reinterpret_cast<const float2*>(s_in + idx);
        acc += wv.x * iv.x + wv.y * iv.y;
    }
    acc = wave_reduce_sum(acc);
    if (lane == 0) out[r] = fmaxf(acc + b[r], 0.f);
}

// Layers 2/3: K = 1024, ONE ROW PER BLOCK. Thread t handles in[4t..4t+3].
// Critical path: 2 coalesced float4 loads -> 4 FMA -> wave reduce ->
// LDS cross-wave add. grid = #rows (1024 or 64).
__global__ void __launch_bounds__(256) fc_relu_row(
        const float* __restrict__ w, const float* __restrict__ b,
        const float* __restrict__ in, float* __restrict__ out) {
    const int row = blockIdx.x;
    const int t = threadIdx.x;

    float4 wv = *reinterpret_cast<const float4*>(w + (size_t)row * 1024 + t * 4);
    float4 iv = *reinterpret_cast<const float4*>(in + t * 4);
    float acc = wv.x * iv.x + wv.y * iv.y + wv.z * iv.z + wv.w * iv.w;
    acc = wave_reduce_sum(acc);

    __shared__ float s[4];
    if ((t & 63) == 0) s[t >> 6] = acc;
    __syncthreads();
    if (t == 0) {
        float tot = s[0] + s[1] + s[2] + s[3];
        out[row] = fmaxf(tot + b[row], 0.f);
    }
}

extern "C" void kernel_launch(void* const* d_in, const int* in_sizes, int n_in,
                              void* d_out, int out_size, void* d_ws, size_t ws_size,
                              hipStream_t stream) {
    // setup_inputs() dict order:
    // 0:x 1:w1_0 2:b1_0 3:w1_1 4:b1_1 5:w1_2 6:b1_2
    // 7..16: w2_*/b2_*  17..26: w3_*/b3_*
    // 27: prev_output 28: state 29: prev_weight_change 30: prev_bias_change
    const float* x    = (const float*)d_in[0];
    const float* w1_0 = (const float*)d_in[1];
    const float* b1_0 = (const float*)d_in[2];
    const float* w1_1 = (const float*)d_in[3];
    const float* b1_1 = (const float*)d_in[4];
    const float* w1_2 = (const float*)d_in[5];
    const float* b1_2 = (const float*)d_in[6];
    const float* po   = (const float*)d_in[27];
    const float* st   = (const float*)d_in[28];

    float* out = (float*)d_out;          // 64 floats
    float* h1 = (float*)d_ws;            // 1024 floats
    float* h2 = h1 + 1024;               // 1024 floats

    fc_relu_concat<<<256, 256, 0, stream>>>(x, po, st, w1_0, b1_0, h1);
    fc_relu_row<<<1024, 256, 0, stream>>>(w1_1, b1_1, h1, h2);
    fc_relu_row<<<64, 256, 0, stream>>>(w1_2, b1_2, h2, out);
}

// Round 6
// 13.265 us; speedup vs baseline: 2.1483x; 1.0240x over previous
//
#include <hip/hip_runtime.h>

// Live computation of the reference (everything else is dead code):
//   inpt[384] = concat(x[64], prev_output[64], state[256])
//   h1[1024]  = relu(w1_0 @ inpt + b1_0)   w1_0: (1024,384) row-major
//   h2[1024]  = relu(w1_1 @ h1   + b1_1)   w1_1: (1024,1024)
//   out[64]   = relu(w1_2 @ h2   + b1_2)   w1_2: (64,1024)
//
// Ledger: 3-dispatch plain (13.6) < 3-dispatch low-occ (15.7) <
// 2-dispatch atomics (19.1) < 1-dispatch lean barrier (28.5) < spin (39.0).
// gfx950 intra-kernel device-scope sync >> kernel-boundary cost; 3 nodes
// is the structural minimum. This round: shave K1's critical path by
// reading the 384-float input directly (L1-resident, same addresses for
// every block) instead of staging through LDS + 2 barriers.

__device__ __forceinline__ float wave_reduce_sum(float v) {
    v += __shfl_xor(v, 32, 64);
    v += __shfl_xor(v, 16, 64);
    v += __shfl_xor(v, 8, 64);
    v += __shfl_xor(v, 4, 64);
    v += __shfl_xor(v, 2, 64);
    v += __shfl_xor(v, 1, 64);
    return v;
}

// Layer 1: K = 384, one row per wave, no LDS, no barriers.
// Segment boundaries (64, 128) are float4/float2-aligned: no vector
// load crosses a source boundary.
__global__ void __launch_bounds__(256) fc_relu_concat(
        const float* __restrict__ x, const float* __restrict__ po,
        const float* __restrict__ st,
        const float* __restrict__ w, const float* __restrict__ b,
        float* __restrict__ out) {
    const int t = threadIdx.x;
    const int lane = t & 63;
    const int wave = t >> 6;
    const int r = blockIdx.x * 4 + wave;   // [0,1024)

    const float* wr = w + (size_t)r * 384;
    float acc;
    {
        const int i = lane * 4;            // [0,256): x / po / st[0..127]
        const float* src = (i < 64) ? (x + i)
                          : (i < 128) ? (po + (i - 64))
                          : (st + (i - 128));
        float4 wv = *reinterpret_cast<const float4*>(wr + i);
        float4 iv = *reinterpret_cast<const float4*>(src);
        acc = wv.x * iv.x + wv.y * iv.y + wv.z * iv.z + wv.w * iv.w;
    }
    {
        const int j = 256 + lane * 2;      // [256,384): st[128..255]
        float2 wv = *reinterpret_cast<const float2*>(wr + j);
        float2 iv = *reinterpret_cast<const float2*>(st + (j - 128));
        acc += wv.x * iv.x + wv.y * iv.y;
    }
    acc = wave_reduce_sum(acc);
    if (lane == 0) out[r] = fmaxf(acc + b[r], 0.f);
}

// Layers 2/3: K = 1024, ONE ROW PER BLOCK. Thread t handles in[4t..4t+3].
// grid = #rows (1024 or 64). 4 blocks/CU -> 16 waves/CU for layer 2.
__global__ void __launch_bounds__(256) fc_relu_row(
        const float* __restrict__ w, const float* __restrict__ b,
        const float* __restrict__ in, float* __restrict__ out) {
    const int row = blockIdx.x;
    const int t = threadIdx.x;

    float4 wv = *reinterpret_cast<const float4*>(w + (size_t)row * 1024 + t * 4);
    float4 iv = *reinterpret_cast<const float4*>(in + t * 4);
    float acc = wv.x * iv.x + wv.y * iv.y + wv.z * iv.z + wv.w * iv.w;
    acc = wave_reduce_sum(acc);

    __shared__ float s[4];
    if ((t & 63) == 0) s[t >> 6] = acc;
    __syncthreads();
    if (t == 0) {
        float tot = s[0] + s[1] + s[2] + s[3];
        out[row] = fmaxf(tot + b[row], 0.f);
    }
}

extern "C" void kernel_launch(void* const* d_in, const int* in_sizes, int n_in,
                              void* d_out, int out_size, void* d_ws, size_t ws_size,
                              hipStream_t stream) {
    // setup_inputs() dict order:
    // 0:x 1:w1_0 2:b1_0 3:w1_1 4:b1_1 5:w1_2 6:b1_2
    // 7..16: w2_*/b2_*  17..26: w3_*/b3_*
    // 27: prev_output 28: state 29: prev_weight_change 30: prev_bias_change
    const float* x    = (const float*)d_in[0];
    const float* w1_0 = (const float*)d_in[1];
    const float* b1_0 = (const float*)d_in[2];
    const float* w1_1 = (const float*)d_in[3];
    const float* b1_1 = (const float*)d_in[4];
    const float* w1_2 = (const float*)d_in[5];
    const float* b1_2 = (const float*)d_in[6];
    const float* po   = (const float*)d_in[27];
    const float* st   = (const float*)d_in[28];

    float* out = (float*)d_out;          // 64 floats
    float* h1 = (float*)d_ws;            // 1024 floats
    float* h2 = h1 + 1024;               // 1024 floats

    fc_relu_concat<<<256, 256, 0, stream>>>(x, po, st, w1_0, b1_0, h1);
    fc_relu_row<<<1024, 256, 0, stream>>>(w1_1, b1_1, h1, h2);
    fc_relu_row<<<64, 256, 0, stream>>>(w1_2, b1_2, h2, out);
}